// Round 2
// baseline (210.720 us; speedup 1.0000x reference)
//
#include <hip/hip_runtime.h>
#include <hip/hip_bf16.h>
#include <math.h>

// ---------------------------------------------------------------------------
// Round 9: split-weight 4-wave pipeline. r8 counters: MfmaUtil 18.7 +
// VALUBusy 37 => 44% stall at 2 waves/SIMD -- occupancy is register-walled
// (each wave holds a full 128-reg weight matrix => ~256 V+A regs/wave).
// Fix: 4 waves/block, each holding HALF a weight matrix (64 regs):
//   waves 0,1: L2 with W2 rows 0-63 / 64-127  (write Y2 halves)
//   waves 2,3: L3+L4 with W3 halves           (read full Y2, partial L4)
//   Y1 lives in LDS (3-deep), built 2 tiles ahead; EACH wave builds one
//   kk-slice (features w*32..w*32+31) -- balanced ~22 VALU/wave/tile.
// One barrier/tile; Y1 lag-2, Y2 lag-1 (WAR/RAW safe). ~145-160 regs/wave
// => __launch_bounds__(256,3) => 3 waves/SIMD (12 waves/CU), per-wave tile
// work halves (16 MFMA). Weight-frag loads hoisted above xmax/hpart so L2
// latency overlaps prologue compute.
// Numerics: Y1 LDS roundtrip is bit-identical (same pk chain, verbatim
// bits); only L4 half-sum association changes (~1e-6). absmax ~0.125.
// ---------------------------------------------------------------------------

#define B_N    16384
#define KQ     51
#define HD     128
#define IND    64
#define BLK    256               // 4 waves
#define RPB    16                // b-rows per block
#define GRID   (B_N / RPB)       // 1024
#define TPB    ((RPB * KQ) / 16) // 51 tiles per block (exact)

typedef __attribute__((ext_vector_type(8))) short short8;
typedef __attribute__((ext_vector_type(4))) float f32x4;

union S8U { short8 s8; unsigned u[4]; };

__device__ __forceinline__ unsigned short f2bf(float f) {
    __hip_bfloat16 t = __float2bfloat16(f);
    return *reinterpret_cast<unsigned short*>(&t);
}

#if defined(__gfx950__) && defined(__has_builtin)
#if __has_builtin(__builtin_amdgcn_cvt_pk_bf16_f32)
#define HAVE_PK_BF16 1
#endif
#endif

__device__ __forceinline__ unsigned pk_bf16(float lo, float hi) {
#ifdef HAVE_PK_BF16
    typedef __attribute__((ext_vector_type(2))) __bf16 bfv2;
    bfv2 r = __builtin_amdgcn_cvt_pk_bf16_f32(lo, hi);
    return *reinterpret_cast<unsigned*>(&r);
#else
    return (unsigned)f2bf(lo) | ((unsigned)f2bf(hi) << 16);
#endif
}

__device__ __forceinline__ float bf_lo(unsigned u) {
    return __uint_as_float(u << 16);
}
__device__ __forceinline__ float bf_hi(unsigned u) {
    return __uint_as_float(u & 0xffff0000u);
}

__launch_bounds__(BLK, 3)
__global__ void umnn_fused(const float* __restrict__ x,  const float* __restrict__ h,
                           const float* __restrict__ W1, const float* __restrict__ b1,
                           const float* __restrict__ W2, const float* __restrict__ b2,
                           const float* __restrict__ W3, const float* __restrict__ b3,
                           const float* __restrict__ W4, const float* __restrict__ b4,
                           float* __restrict__ out)
{
    __shared__ __align__(16) float hpL[RPB * HD];      // 8 KB block hpart
    __shared__ __align__(16) char  y1x[3][4096];       // 12 KB Y1 triple buffer
    __shared__ __align__(16) char  y2x[2][4096];       // 8 KB Y2 double buffer
    __shared__ __align__(16) float hshT[63 * 20];      // 5 KB h^T staging
    __shared__ float vs2[2][RPB * KQ + 16];            // 6.6 KB L4 half-partials
    __shared__ float xL[RPB];
    __shared__ float sSteps[KQ], sCcw[KQ];
    __shared__ float red4[4];

    const int tid  = threadIdx.x;
    const int w    = tid >> 6;          // wave 0..3
    const int lane = tid & 63;
    const int q    = lane >> 4;
    const int lm   = lane & 15;
    const int swz  = lm & 7;
    const bool isL2 = (w < 2);
    const int ntB  = (w & 1) * 4;       // nt half: rows ntB*16 .. ntB*16+63
    const int rowBase = blockIdx.x * RPB;

    // ---- CC tables (validated r4 formula) ----
    if (tid < KQ) {
        const int j = tid;
        const float pi50 = 0.06283185307179586f;
        sSteps[j] = __cosf((float)j * pi50);
        float s = 0.0f;
        for (int i = 0; i <= 50; i += 2) {
            float Wi = (i == 0) ? 1.0f : 2.0f / (1.0f - (float)(i * i));
            float lam;
            if (j == 0) lam = 0.5f;
            else {
                int mp = (i * j) % 100;
                lam = __cosf((float)mp * pi50);
                if (j == 50) lam *= 0.5f;
            }
            s += (lam * 0.04f) * Wi;
        }
        sCcw[j] = s;
    }

    // ---- hoisted weight-fragment loads (overlap L2 latency w/ prologue) ----
    const float* Wsel = isL2 ? W2 : W3;
    const float* bsel = isL2 ? b2 : b3;
    short8  WA[4][4];
    unsigned bp[8];
    #pragma unroll
    for (int nt = 0; nt < 4; ++nt) {
        #pragma unroll
        for (int kk = 0; kk < 4; ++kk) {
            const float* p = Wsel + ((ntB + nt) * 16 + lm) * HD + kk * 32 + q * 8;
            S8U a;
            #pragma unroll
            for (int j = 0; j < 4; ++j)
                a.u[j] = pk_bf16(p[2 * j], p[2 * j + 1]);
            WA[nt][kk] = a.s8;
        }
        bp[2 * nt + 0] = pk_bf16(bsel[(ntB + nt) * 16 + q * 4 + 0],
                                 bsel[(ntB + nt) * 16 + q * 4 + 1]);
        bp[2 * nt + 1] = pk_bf16(bsel[(ntB + nt) * 16 + q * 4 + 2],
                                 bsel[(ntB + nt) * 16 + q * 4 + 3]);
    }
    f32x4 W4c[4];
    if (!isL2) {
        #pragma unroll
        for (int nt = 0; nt < 4; ++nt)
            W4c[nt] = *(const f32x4*)(W4 + (ntB + nt) * 16 + q * 4);
    }
    const float b4v = b4[0];
    float w1x[8];                       // this wave's kk = w feature slice
    #pragma unroll
    for (int j = 0; j < 8; ++j)
        w1x[j] = W1[(w * 32 + q * 8 + j) * IND];

    // ---- xmax scan (x: 64 KB, cache-resident) ----
    {
        const f32x4* x4 = (const f32x4*)x;
        float mx = -1e30f;
        for (int i = tid; i < B_N / 4; i += BLK) {
            f32x4 v = x4[i];
            mx = fmaxf(fmaxf(mx, fmaxf(v[0], v[1])), fmaxf(v[2], v[3]));
        }
        #pragma unroll
        for (int d = 32; d > 0; d >>= 1) mx = fmaxf(mx, __shfl_xor(mx, d));
        if (lane == 0) red4[w] = mx;
    }
    // ---- stage h^T for this block's 16 rows; init xL ----
    for (int i = tid; i < RPB * 63; i += BLK) {
        int r = i / 63, d = i - r * 63;
        hshT[d * 20 + r] = h[rowBase * 63 + i];
    }
    if (tid < RPB) xL[tid] = x[rowBase + tid];
    __syncthreads();                                   // B1

    const float xmax = fmaxf(fmaxf(red4[0], red4[1]),
                             fmaxf(red4[2], red4[3])) + 10.0f;

    // ---- block hpart: thread = feature (tid&127), 8 rows per half ----
    {
        const int n  = tid & 127;
        const int rh = (tid >> 7) * 8;  // rows rh..rh+7
        float acc[8];
        const float b1v = b1[n];
        #pragma unroll
        for (int r = 0; r < 8; ++r) acc[r] = b1v;
        const float* wr = W1 + n * IND + 1;
        #pragma unroll 1
        for (int d = 0; d < IND - 1; ++d) {
            float wv = wr[d];
            const float* ht = hshT + d * 20 + rh;
            f32x4 hv0 = *(const f32x4*)ht;
            f32x4 hv1 = *(const f32x4*)(ht + 4);
            acc[0] = fmaf(wv, hv0[0], acc[0]);
            acc[1] = fmaf(wv, hv0[1], acc[1]);
            acc[2] = fmaf(wv, hv0[2], acc[2]);
            acc[3] = fmaf(wv, hv0[3], acc[3]);
            acc[4] = fmaf(wv, hv1[0], acc[4]);
            acc[5] = fmaf(wv, hv1[1], acc[5]);
            acc[6] = fmaf(wv, hv1[2], acc[6]);
            acc[7] = fmaf(wv, hv1[3], acc[7]);
        }
        #pragma unroll
        for (int r = 0; r < 8; ++r) hpL[(rh + r) * HD + n] = acc[r];
    }
    __syncthreads();                                   // B2 (hpL ready)

    // ---- per-lane constant LDS offsets ----
    int rdOff[4];
    #pragma unroll
    for (int kk = 0; kk < 4; ++kk)
        rdOff[kk] = lm * 256 + (((kk * 4 + q) ^ swz) << 4);
    const int bldOff = lm * 256 + (((w * 4 + q) ^ swz) << 4);
    int wrOff[4];
    #pragma unroll
    for (int nt = 0; nt < 4; ++nt)
        wrOff[nt] = lm * 256 + (((2 * (ntB + nt) + (q >> 1)) ^ swz) << 4) + ((q & 1) << 3);
    float* vsW = vs2[w & 1];

    // Y1 builder: this wave contributes kk = w (features w*32 .. w*32+31)
    auto buildY1 = [&](int ib, char* dst) {
        const int s   = ib * 16 + lm;          // 0..815
        const int row = s / KQ;                // 0..15
        const int k   = s - row * KQ;          // 0..50
        const float x0 = xL[row];
        const float X  = fmaf((xmax - x0) * 0.5f, sSteps[k] + 1.0f, x0);
        const float* hp = hpL + row * HD + w * 32 + q * 8;
        f32x4 ha = *(const f32x4*)hp;
        f32x4 hb = *(const f32x4*)(hp + 4);
        S8U u;
        u.u[0] = pk_bf16(fmaxf(fmaf(X, w1x[0], ha[0]), 0.f),
                         fmaxf(fmaf(X, w1x[1], ha[1]), 0.f));
        u.u[1] = pk_bf16(fmaxf(fmaf(X, w1x[2], ha[2]), 0.f),
                         fmaxf(fmaf(X, w1x[3], ha[3]), 0.f));
        u.u[2] = pk_bf16(fmaxf(fmaf(X, w1x[4], hb[0]), 0.f),
                         fmaxf(fmaf(X, w1x[5], hb[1]), 0.f));
        u.u[3] = pk_bf16(fmaxf(fmaf(X, w1x[6], hb[2]), 0.f),
                         fmaxf(fmaf(X, w1x[7], hb[3]), 0.f));
        *(short8*)(dst + bldOff) = u.s8;
    };

    // prologue: tiles 0,1 into Y1 buffers 0,1
    buildY1(0, y1x[0]);
    buildY1(1, y1x[1]);
    __syncthreads();                                   // B3

    // ============ pipelined loop: one barrier per tile ============
    // iter i: L2 waves do tile i; L3 waves do tile i-1; all build tile i+2.
    int br = 0, bw = 2;
    #pragma unroll 1
    for (int i = 0; i <= TPB; ++i) {
        const bool act = isL2 ? (i < TPB) : (i >= 1);
        const char* src = isL2 ? (const char*)y1x[br]
                               : (const char*)y2x[(i + 1) & 1];   // (i-1)&1
        short8 Yf[4];
        if (act) {
            #pragma unroll
            for (int kk = 0; kk < 4; ++kk)
                Yf[kk] = *(const short8*)(src + rdOff[kk]);
        }
        if (i + 2 < TPB) buildY1(i + 2, y1x[bw]);

        if (act) {
            f32x4 C[4];
            #pragma unroll
            for (int nt = 0; nt < 4; ++nt) {
                unsigned u0 = bp[2 * nt], u1 = bp[2 * nt + 1];
                C[nt][0] = bf_lo(u0); C[nt][1] = bf_hi(u0);
                C[nt][2] = bf_lo(u1); C[nt][3] = bf_hi(u1);
            }
            #pragma unroll
            for (int kk = 0; kk < 4; ++kk)
                #pragma unroll
                for (int nt = 0; nt < 4; ++nt)
                    C[nt] = __builtin_amdgcn_mfma_f32_16x16x32_bf16(WA[nt][kk], Yf[kk], C[nt], 0, 0, 0);

            if (isL2) {
                // pack + write this wave's Y2 half
                char* d2 = y2x[i & 1];
                #pragma unroll
                for (int nt = 0; nt < 4; ++nt) {
                    unsigned lo = pk_bf16(fmaxf(C[nt][0], 0.f), fmaxf(C[nt][1], 0.f));
                    unsigned hi = pk_bf16(fmaxf(C[nt][2], 0.f), fmaxf(C[nt][3], 0.f));
                    *(int2*)(d2 + wrOff[nt]) = make_int2((int)lo, (int)hi);
                }
            } else {
                // L4 half-partial: q-reduce, defer the rest
                float pa = 0.f;
                #pragma unroll
                for (int nt = 0; nt < 4; ++nt) {
                    pa = fmaf(fmaxf(C[nt][0], 0.f), W4c[nt][0], pa);
                    pa = fmaf(fmaxf(C[nt][1], 0.f), W4c[nt][1], pa);
                    pa = fmaf(fmaxf(C[nt][2], 0.f), W4c[nt][2], pa);
                    pa = fmaf(fmaxf(C[nt][3], 0.f), W4c[nt][3], pa);
                }
                pa += __shfl_xor(pa, 16);
                pa += __shfl_xor(pa, 32);
                if (lane < 16) vsW[(i - 1) * 16 + lm] = pa;
            }
        }
        __syncthreads();                               // tile rendezvous
        br = (br == 2) ? 0 : br + 1;
        bw = (bw == 2) ? 0 : bw + 1;
    }

    // ---- deferred epilogue: sum halves, elu + ccw + row-reduce ----
    if (w == 0) {
        const int r   = lane >> 2;                     // row 0..15
        const int sub = lane & 3;
        float a = 0.f;
        #pragma unroll 1
        for (int j = 0; j < 13; ++j) {
            int k = sub + 4 * j;
            if (k < KQ) {
                float y4 = vs2[0][r * KQ + k] + vs2[1][r * KQ + k] + b4v;
                float f  = (y4 > 0.f) ? (y4 + 1.f) : __expf(y4);
                a = fmaf(f, sCcw[k], a);
            }
        }
        a += __shfl_xor(a, 1);
        a += __shfl_xor(a, 2);
        if (sub == 0)
            out[rowBase + r] = a * (xmax - xL[r]) * 0.5f;
    }
}

// ---------------------------------------------------------------------------
extern "C" void kernel_launch(void* const* d_in, const int* in_sizes, int n_in,
                              void* d_out, int out_size, void* d_ws, size_t ws_size,
                              hipStream_t stream)
{
    const float* x  = (const float*)d_in[0];
    const float* h  = (const float*)d_in[1];
    const float* W1 = (const float*)d_in[2];
    const float* b1 = (const float*)d_in[3];
    const float* W2 = (const float*)d_in[4];
    const float* b2 = (const float*)d_in[5];
    const float* W3 = (const float*)d_in[6];
    const float* b3 = (const float*)d_in[7];
    const float* W4 = (const float*)d_in[8];
    const float* b4 = (const float*)d_in[9];
    float* out = (float*)d_out;

    umnn_fused<<<GRID, BLK, 0, stream>>>(x, h, W1, b1, W2, b2, W3, b3,
                                         W4, b4, out);
}

// Round 3
// 200.091 us; speedup vs baseline: 1.0531x; 1.0531x over previous
//
#include <hip/hip_runtime.h>
#include <hip/hip_bf16.h>
#include <math.h>

// ---------------------------------------------------------------------------
// Round 10: r9 dataflow, r8 code structure. r9 post-mortem: WRITE_SIZE 52 MB
// (scratch spills) + occupancy stuck at 2 waves/SIMD -- the MERGED role loop
// (if(act){...} with lambda-captured rotation state) blew the live-range
// budget and the allocator spilled the hot loop at VGPR_Count=84.
// Fix: identical 4-wave split-weight pipeline (proven correct in r9), but as
// TWO DISJOINT role loops so each role allocates independently:
//   producer (w=0,1): read Y1(j) -> 16 MFMA (W2 half) -> pack Y2 half
//                     -> build Y1(j+1) slice -> barrier        [TPB+1 bars]
//   consumer (w=2,3): read Y2(j-1) -> 16 MFMA (W3 half) -> L4 half-partial
//                     -> build Y1(j+1) slice -> barrier        [TPB+1 bars]
// Y1: 2 buffers (lag analysis: build j+1 vs read j never collide), guarded
// builds (j+1<TPB) instead of clamped overrun. Per-role live state ~135 regs
// < 170 budget of __launch_bounds__(256,3) => 3 blocks/CU (12 waves/CU).
// Numerics: bit-identical chain to r9 (which passed, absmax 0.125).
// ---------------------------------------------------------------------------

#define B_N    16384
#define KQ     51
#define HD     128
#define IND    64
#define BLK    256               // 4 waves
#define RPB    16                // b-rows per block
#define GRID   (B_N / RPB)       // 1024
#define TPB    ((RPB * KQ) / 16) // 51 tiles per block (exact)

typedef __attribute__((ext_vector_type(8))) short short8;
typedef __attribute__((ext_vector_type(4))) float f32x4;

union S8U { short8 s8; unsigned u[4]; };

__device__ __forceinline__ unsigned short f2bf(float f) {
    __hip_bfloat16 t = __float2bfloat16(f);
    return *reinterpret_cast<unsigned short*>(&t);
}

#if defined(__gfx950__) && defined(__has_builtin)
#if __has_builtin(__builtin_amdgcn_cvt_pk_bf16_f32)
#define HAVE_PK_BF16 1
#endif
#endif

__device__ __forceinline__ unsigned pk_bf16(float lo, float hi) {
#ifdef HAVE_PK_BF16
    typedef __attribute__((ext_vector_type(2))) __bf16 bfv2;
    bfv2 r = __builtin_amdgcn_cvt_pk_bf16_f32(lo, hi);
    return *reinterpret_cast<unsigned*>(&r);
#else
    return (unsigned)f2bf(lo) | ((unsigned)f2bf(hi) << 16);
#endif
}

__device__ __forceinline__ float bf_lo(unsigned u) {
    return __uint_as_float(u << 16);
}
__device__ __forceinline__ float bf_hi(unsigned u) {
    return __uint_as_float(u & 0xffff0000u);
}

__launch_bounds__(BLK, 3)
__global__ void umnn_fused(const float* __restrict__ x,  const float* __restrict__ h,
                           const float* __restrict__ W1, const float* __restrict__ b1,
                           const float* __restrict__ W2, const float* __restrict__ b2,
                           const float* __restrict__ W3, const float* __restrict__ b3,
                           const float* __restrict__ W4, const float* __restrict__ b4,
                           float* __restrict__ out)
{
    __shared__ __align__(16) float hpL[RPB * HD];      // 8 KB block hpart
    __shared__ __align__(16) char  y1x[2][4096];       // 8 KB Y1 double buffer
    __shared__ __align__(16) char  y2x[2][4096];       // 8 KB Y2 double buffer
    __shared__ __align__(16) float hshT[63 * 20];      // 5 KB h^T staging
    __shared__ float vs2[2][RPB * KQ + 16];            // 6.6 KB L4 half-partials
    __shared__ float xL[RPB];
    __shared__ float sSteps[KQ], sCcw[KQ];
    __shared__ float red4[4];

    const int tid  = threadIdx.x;
    const int w    = tid >> 6;          // wave 0..3
    const int lane = tid & 63;
    const int q    = lane >> 4;
    const int lm   = lane & 15;
    const int swz  = lm & 7;
    const bool isL2 = (w < 2);
    const int ntB  = (w & 1) * 4;       // weight half: rows ntB*16 .. +63
    const int rowBase = blockIdx.x * RPB;

    // ---- CC tables (validated r4 formula) ----
    if (tid < KQ) {
        const int j = tid;
        const float pi50 = 0.06283185307179586f;
        sSteps[j] = __cosf((float)j * pi50);
        float s = 0.0f;
        for (int i = 0; i <= 50; i += 2) {
            float Wi = (i == 0) ? 1.0f : 2.0f / (1.0f - (float)(i * i));
            float lam;
            if (j == 0) lam = 0.5f;
            else {
                int mp = (i * j) % 100;
                lam = __cosf((float)mp * pi50);
                if (j == 50) lam *= 0.5f;
            }
            s += (lam * 0.04f) * Wi;
        }
        sCcw[j] = s;
    }

    // ---- hoisted weight-fragment loads (L2 latency under prologue) ----
    const float* Wsel = isL2 ? W2 : W3;
    const float* bsel = isL2 ? b2 : b3;
    short8  WA[4][4];
    unsigned bp[8];
    #pragma unroll
    for (int nt = 0; nt < 4; ++nt) {
        #pragma unroll
        for (int kk = 0; kk < 4; ++kk) {
            const float* p = Wsel + ((ntB + nt) * 16 + lm) * HD + kk * 32 + q * 8;
            S8U a;
            #pragma unroll
            for (int j = 0; j < 4; ++j)
                a.u[j] = pk_bf16(p[2 * j], p[2 * j + 1]);
            WA[nt][kk] = a.s8;
        }
        bp[2 * nt + 0] = pk_bf16(bsel[(ntB + nt) * 16 + q * 4 + 0],
                                 bsel[(ntB + nt) * 16 + q * 4 + 1]);
        bp[2 * nt + 1] = pk_bf16(bsel[(ntB + nt) * 16 + q * 4 + 2],
                                 bsel[(ntB + nt) * 16 + q * 4 + 3]);
    }
    f32x4 W4c[4];
    if (!isL2) {
        #pragma unroll
        for (int nt = 0; nt < 4; ++nt)
            W4c[nt] = *(const f32x4*)(W4 + (ntB + nt) * 16 + q * 4);
    }
    const float b4v = b4[0];
    float w1x[8];                       // this wave's kk = w feature slice
    #pragma unroll
    for (int j = 0; j < 8; ++j)
        w1x[j] = W1[(w * 32 + q * 8 + j) * IND];

    // ---- xmax scan (x: 64 KB, cache-resident) ----
    {
        const f32x4* x4 = (const f32x4*)x;
        float mx = -1e30f;
        for (int i = tid; i < B_N / 4; i += BLK) {
            f32x4 v = x4[i];
            mx = fmaxf(fmaxf(mx, fmaxf(v[0], v[1])), fmaxf(v[2], v[3]));
        }
        #pragma unroll
        for (int d = 32; d > 0; d >>= 1) mx = fmaxf(mx, __shfl_xor(mx, d));
        if (lane == 0) red4[w] = mx;
    }
    // ---- stage h^T for this block's 16 rows; init xL ----
    for (int i = tid; i < RPB * 63; i += BLK) {
        int r = i / 63, d = i - r * 63;
        hshT[d * 20 + r] = h[rowBase * 63 + i];
    }
    if (tid < RPB) xL[tid] = x[rowBase + tid];
    __syncthreads();                                   // B1

    const float xmax = fmaxf(fmaxf(red4[0], red4[1]),
                             fmaxf(red4[2], red4[3])) + 10.0f;

    // ---- block hpart: thread = feature (tid&127), 8 rows per half ----
    {
        const int n  = tid & 127;
        const int rh = (tid >> 7) * 8;  // rows rh..rh+7
        float acc[8];
        const float b1v = b1[n];
        #pragma unroll
        for (int r = 0; r < 8; ++r) acc[r] = b1v;
        const float* wr = W1 + n * IND + 1;
        #pragma unroll 1
        for (int d = 0; d < IND - 1; ++d) {
            float wv = wr[d];
            const float* ht = hshT + d * 20 + rh;
            f32x4 hv0 = *(const f32x4*)ht;
            f32x4 hv1 = *(const f32x4*)(ht + 4);
            acc[0] = fmaf(wv, hv0[0], acc[0]);
            acc[1] = fmaf(wv, hv0[1], acc[1]);
            acc[2] = fmaf(wv, hv0[2], acc[2]);
            acc[3] = fmaf(wv, hv0[3], acc[3]);
            acc[4] = fmaf(wv, hv1[0], acc[4]);
            acc[5] = fmaf(wv, hv1[1], acc[5]);
            acc[6] = fmaf(wv, hv1[2], acc[6]);
            acc[7] = fmaf(wv, hv1[3], acc[7]);
        }
        #pragma unroll
        for (int r = 0; r < 8; ++r) hpL[(rh + r) * HD + n] = acc[r];
    }
    __syncthreads();                                   // B2 (hpL ready)

    // ---- per-lane constant LDS offsets (layout math verbatim from r9) ----
    int rdOff[4];                                      // full-frag read (Y1/Y2)
    #pragma unroll
    for (int kk = 0; kk < 4; ++kk)
        rdOff[kk] = lm * 256 + (((kk * 4 + q) ^ swz) << 4);
    const int bldOff = lm * 256 + (((w * 4 + q) ^ swz) << 4);

    // Y1 builder: this wave contributes kk = w (features w*32 .. w*32+31)
    auto buildY1 = [&](int ib, char* dst) {
        const int s   = ib * 16 + lm;          // 0..815 (guarded: never 816+)
        const int row = s / KQ;                // 0..15
        const int k   = s - row * KQ;          // 0..50
        const float x0 = xL[row];
        const float X  = fmaf((xmax - x0) * 0.5f, sSteps[k] + 1.0f, x0);
        const float* hp = hpL + row * HD + w * 32 + q * 8;
        f32x4 ha = *(const f32x4*)hp;
        f32x4 hb = *(const f32x4*)(hp + 4);
        S8U u;
        u.u[0] = pk_bf16(fmaxf(fmaf(X, w1x[0], ha[0]), 0.f),
                         fmaxf(fmaf(X, w1x[1], ha[1]), 0.f));
        u.u[1] = pk_bf16(fmaxf(fmaf(X, w1x[2], ha[2]), 0.f),
                         fmaxf(fmaf(X, w1x[3], ha[3]), 0.f));
        u.u[2] = pk_bf16(fmaxf(fmaf(X, w1x[4], hb[0]), 0.f),
                         fmaxf(fmaf(X, w1x[5], hb[1]), 0.f));
        u.u[3] = pk_bf16(fmaxf(fmaf(X, w1x[6], hb[2]), 0.f),
                         fmaxf(fmaf(X, w1x[7], hb[3]), 0.f));
        *(short8*)(dst + bldOff) = u.s8;
    };

    // prologue: all 4 waves build their slice of tile 0
    buildY1(0, y1x[0]);
    __syncthreads();                                   // B3

    if (isL2) {
        // =============== PRODUCER loop: TPB iters + 1 match-barrier ========
        int wrOff[4];
        #pragma unroll
        for (int nt = 0; nt < 4; ++nt)
            wrOff[nt] = lm * 256 + (((2 * (ntB + nt) + (q >> 1)) ^ swz) << 4)
                      + ((q & 1) << 3);
        #pragma unroll 1
        for (int j = 0; j < TPB; ++j) {
            const char* src = y1x[j & 1];
            short8 Yf[4];
            #pragma unroll
            for (int kk = 0; kk < 4; ++kk)
                Yf[kk] = *(const short8*)(src + rdOff[kk]);

            f32x4 C[4];
            #pragma unroll
            for (int nt = 0; nt < 4; ++nt) {
                unsigned u0 = bp[2 * nt], u1 = bp[2 * nt + 1];
                C[nt][0] = bf_lo(u0); C[nt][1] = bf_hi(u0);
                C[nt][2] = bf_lo(u1); C[nt][3] = bf_hi(u1);
            }
            #pragma unroll
            for (int kk = 0; kk < 4; ++kk)
                #pragma unroll
                for (int nt = 0; nt < 4; ++nt)
                    C[nt] = __builtin_amdgcn_mfma_f32_16x16x32_bf16(WA[nt][kk], Yf[kk], C[nt], 0, 0, 0);

            char* d2 = y2x[j & 1];
            #pragma unroll
            for (int nt = 0; nt < 4; ++nt) {
                unsigned lo = pk_bf16(fmaxf(C[nt][0], 0.f), fmaxf(C[nt][1], 0.f));
                unsigned hi = pk_bf16(fmaxf(C[nt][2], 0.f), fmaxf(C[nt][3], 0.f));
                *(int2*)(d2 + wrOff[nt]) = make_int2((int)lo, (int)hi);
            }
            if (j + 1 < TPB) buildY1(j + 1, y1x[(j + 1) & 1]);
            __syncthreads();                           // barrier j+1
        }
        __syncthreads();                               // match consumer tail
    } else {
        // =============== CONSUMER loop: lag-1, TPB iters + tail ===========
        float* vsW = vs2[w & 1];
        // j = 0: nothing to consume yet; build tile 1
        buildY1(1, y1x[1]);
        __syncthreads();                               // barrier 1
        #pragma unroll 1
        for (int j = 1; j < TPB; ++j) {
            const char* src = y2x[(j - 1) & 1];
            short8 Yf[4];
            #pragma unroll
            for (int kk = 0; kk < 4; ++kk)
                Yf[kk] = *(const short8*)(src + rdOff[kk]);

            f32x4 C[4];
            #pragma unroll
            for (int nt = 0; nt < 4; ++nt) {
                unsigned u0 = bp[2 * nt], u1 = bp[2 * nt + 1];
                C[nt][0] = bf_lo(u0); C[nt][1] = bf_hi(u0);
                C[nt][2] = bf_lo(u1); C[nt][3] = bf_hi(u1);
            }
            #pragma unroll
            for (int kk = 0; kk < 4; ++kk)
                #pragma unroll
                for (int nt = 0; nt < 4; ++nt)
                    C[nt] = __builtin_amdgcn_mfma_f32_16x16x32_bf16(WA[nt][kk], Yf[kk], C[nt], 0, 0, 0);

            float pa = 0.f;
            #pragma unroll
            for (int nt = 0; nt < 4; ++nt) {
                pa = fmaf(fmaxf(C[nt][0], 0.f), W4c[nt][0], pa);
                pa = fmaf(fmaxf(C[nt][1], 0.f), W4c[nt][1], pa);
                pa = fmaf(fmaxf(C[nt][2], 0.f), W4c[nt][2], pa);
                pa = fmaf(fmaxf(C[nt][3], 0.f), W4c[nt][3], pa);
            }
            pa += __shfl_xor(pa, 16);
            pa += __shfl_xor(pa, 32);
            if (lane < 16) vsW[(j - 1) * 16 + lm] = pa;

            if (j + 1 < TPB) buildY1(j + 1, y1x[(j + 1) & 1]);
            __syncthreads();                           // barrier j+1
        }
        // tail: tile TPB-1 (written by producer before barrier TPB)
        {
            const char* src = y2x[(TPB - 1) & 1];
            short8 Yf[4];
            #pragma unroll
            for (int kk = 0; kk < 4; ++kk)
                Yf[kk] = *(const short8*)(src + rdOff[kk]);

            f32x4 C[4];
            #pragma unroll
            for (int nt = 0; nt < 4; ++nt) {
                unsigned u0 = bp[2 * nt], u1 = bp[2 * nt + 1];
                C[nt][0] = bf_lo(u0); C[nt][1] = bf_hi(u0);
                C[nt][2] = bf_lo(u1); C[nt][3] = bf_hi(u1);
            }
            #pragma unroll
            for (int kk = 0; kk < 4; ++kk)
                #pragma unroll
                for (int nt = 0; nt < 4; ++nt)
                    C[nt] = __builtin_amdgcn_mfma_f32_16x16x32_bf16(WA[nt][kk], Yf[kk], C[nt], 0, 0, 0);

            float pa = 0.f;
            #pragma unroll
            for (int nt = 0; nt < 4; ++nt) {
                pa = fmaf(fmaxf(C[nt][0], 0.f), W4c[nt][0], pa);
                pa = fmaf(fmaxf(C[nt][1], 0.f), W4c[nt][1], pa);
                pa = fmaf(fmaxf(C[nt][2], 0.f), W4c[nt][2], pa);
                pa = fmaf(fmaxf(C[nt][3], 0.f), W4c[nt][3], pa);
            }
            pa += __shfl_xor(pa, 16);
            pa += __shfl_xor(pa, 32);
            if (lane < 16) vsW[(TPB - 1) * 16 + lm] = pa;
        }
        __syncthreads();                               // final barrier
    }

    // ---- deferred epilogue: sum halves, elu + ccw + row-reduce ----
    if (w == 0) {
        const int r   = lane >> 2;                     // row 0..15
        const int sub = lane & 3;
        float a = 0.f;
        #pragma unroll 1
        for (int j = 0; j < 13; ++j) {
            int k = sub + 4 * j;
            if (k < KQ) {
                float y4 = vs2[0][r * KQ + k] + vs2[1][r * KQ + k] + b4v;
                float f  = (y4 > 0.f) ? (y4 + 1.f) : __expf(y4);
                a = fmaf(f, sCcw[k], a);
            }
        }
        a += __shfl_xor(a, 1);
        a += __shfl_xor(a, 2);
        if (sub == 0)
            out[rowBase + r] = a * (xmax - xL[r]) * 0.5f;
    }
}

// ---------------------------------------------------------------------------
extern "C" void kernel_launch(void* const* d_in, const int* in_sizes, int n_in,
                              void* d_out, int out_size, void* d_ws, size_t ws_size,
                              hipStream_t stream)
{
    const float* x  = (const float*)d_in[0];
    const float* h  = (const float*)d_in[1];
    const float* W1 = (const float*)d_in[2];
    const float* b1 = (const float*)d_in[3];
    const float* W2 = (const float*)d_in[4];
    const float* b2 = (const float*)d_in[5];
    const float* W3 = (const float*)d_in[6];
    const float* b3 = (const float*)d_in[7];
    const float* W4 = (const float*)d_in[8];
    const float* b4 = (const float*)d_in[9];
    float* out = (float*)d_out;

    umnn_fused<<<GRID, BLK, 0, stream>>>(x, h, W1, b1, W2, b2, W3, b3,
                                         W4, b4, out);
}